// Round 1
// baseline (540.838 us; speedup 1.0000x reference)
//
#include <hip/hip_runtime.h>

// FlowNet correlation, max_disp=4 -> 81 displacement channels, mean over C, LeakyReLU(0.1).
// B=8 C=128 H=128 W=256 fp32 NCHW.
//
// Design: block = 576 threads = 9 waves; wave wv handles displacement row dy=wv.
// Lane owns 8 consecutive pixels of an 8x64 spatial tile -> acc[9 dx][8 px] in regs.
// x2 halo tile (16 x 72, stride 76 for bank-conflict-free ds_read_b128) staged in
// double-buffered LDS, 4 channels per chunk. x1 read direct from global (coalesced,
// 9x wave reuse via L1) with register ping-pong prefetch.

constexpr int MAXD = 4;
constexpr int ND   = 9;            // displacements per axis
constexpr int NDISP = 81;
constexpr int Bb = 8, Cc = 128, Hh = 128, Ww = 256;
constexpr int TH = 8, TW = 64, NPIX = 8;
constexpr int CK = 4;              // channels per staged chunk
constexpr int NCHUNK = Cc / CK;    // 32
constexpr int XROWS = TH + 2 * MAXD;   // 16
constexpr int XSTR  = 76;              // padded row stride (72 used) -> all 32 banks hit
constexpr int CH_TILE = XROWS * XSTR;  // 1216 floats / channel
constexpr int BUFF = CK * CH_TILE;     // 4864 floats / buffer
constexpr int NTHREADS = ND * 64;      // 576
constexpr int HW = Hh * Ww;            // 32768
constexpr float SCALE = 1.0f / 128.0f;
constexpr float SLOPE = 0.1f;

__global__ __launch_bounds__(NTHREADS, 4)
void corr81_kernel(const float* __restrict__ x1, const float* __restrict__ x2,
                   float* __restrict__ out) {
  const int tid = threadIdx.x;
  const int wv  = tid >> 6;          // dy = wv, 0..8
  const int l   = tid & 63;
  const int r   = l >> 3;            // pixel row in tile, 0..7
  const int cb  = (l & 7) << 3;      // pixel col base, 0..56

  const int w0 = blockIdx.x * TW;
  const int h0 = blockIdx.y * TH;
  const int b  = blockIdx.z;

  __shared__ float x2s[2 * BUFF];    // 38912 B

  // --- staging coords: 576 threads x one float2 = 16 rows x 72 cols per channel
  const int srow = tid / 36;                 // 0..15
  const int scol = (tid - srow * 36) * 2;    // 0..70, even
  const int gh2  = h0 - MAXD + srow;
  const int gw2  = w0 - MAXD + scol;
  const bool sok = (gh2 >= 0) && (gh2 < Hh) && (gw2 >= 0) && (gw2 < Ww);
  const int x2base = b * (Cc * HW) + gh2 * Ww + gw2;   // valid only when sok
  const int sldso  = srow * XSTR + scol;

  // --- compute-side addresses
  const int x1base = (b * Cc * Hh + h0 + r) * Ww + w0 + cb;
  const int ldro   = (r + wv) * XSTR + cb;   // LDS row (r+dy), col cb (reads cb..cb+15)

  float acc[ND][NPIX];
#pragma unroll
  for (int dx = 0; dx < ND; ++dx)
#pragma unroll
    for (int i = 0; i < NPIX; ++i) acc[dx][i] = 0.0f;

  float a[2][NPIX];  // x1 ping-pong: channel parity ch&1

  auto loadx1 = [&](int ch, float* dst) {
    const float* p = x1 + x1base + ch * HW;
    float4 t0 = *reinterpret_cast<const float4*>(p);
    float4 t1 = *reinterpret_cast<const float4*>(p + 4);
    dst[0] = t0.x; dst[1] = t0.y; dst[2] = t0.z; dst[3] = t0.w;
    dst[4] = t1.x; dst[5] = t1.y; dst[6] = t1.z; dst[7] = t1.w;
  };

  // --- prologue: stage chunk 0, load x1 channel 0
#pragma unroll
  for (int c = 0; c < CK; ++c) {
    float2 v = make_float2(0.0f, 0.0f);
    if (sok) v = *reinterpret_cast<const float2*>(x2 + x2base + c * HW);
    *reinterpret_cast<float2*>(&x2s[c * CH_TILE + sldso]) = v;
  }
  loadx1(0, a[0]);
  __syncthreads();

  for (int k = 0; k < NCHUNK; ++k) {
    const int kn = k + 1;
    float2 sreg[CK];
    if (kn < NCHUNK) {  // issue next chunk's global loads early
#pragma unroll
      for (int c = 0; c < CK; ++c) {
        float2 v = make_float2(0.0f, 0.0f);
        if (sok) v = *reinterpret_cast<const float2*>(x2 + x2base + (kn * CK + c) * HW);
        sreg[c] = v;
      }
    }
    const float* lb = &x2s[(k & 1) * BUFF + ldro];
#pragma unroll
    for (int c = 0; c < CK; ++c) {
      const int ch = k * CK + c;
      int chn = ch + 1; if (chn >= Cc) chn = Cc - 1;   // clamped tail prefetch
      loadx1(chn, a[(c + 1) & 1]);

      const float* lp = lb + c * CH_TILE;
      float4 q0 = *reinterpret_cast<const float4*>(lp);
      float4 q1 = *reinterpret_cast<const float4*>(lp + 4);
      float4 q2 = *reinterpret_cast<const float4*>(lp + 8);
      float4 q3 = *reinterpret_cast<const float4*>(lp + 12);
      float xr[16] = {q0.x, q0.y, q0.z, q0.w, q1.x, q1.y, q1.z, q1.w,
                      q2.x, q2.y, q2.z, q2.w, q3.x, q3.y, q3.z, q3.w};
      const float* av = a[c & 1];
#pragma unroll
      for (int dx = 0; dx < ND; ++dx)
#pragma unroll
        for (int i = 0; i < NPIX; ++i)
          acc[dx][i] = fmaf(av[i], xr[i + dx], acc[dx][i]);
    }
    if (kn < NCHUNK) {  // commit next chunk into the other buffer
#pragma unroll
      for (int c = 0; c < CK; ++c)
        *reinterpret_cast<float2*>(&x2s[(kn & 1) * BUFF + c * CH_TILE + sldso]) = sreg[c];
    }
    __syncthreads();
  }

  // --- epilogue: mean + LeakyReLU + coalesced float4 stores
  const int obase = (b * NDISP + wv * ND) * HW + (h0 + r) * Ww + w0 + cb;
#pragma unroll
  for (int dx = 0; dx < ND; ++dx) {
    float4 v0, v1;
    float t;
    t = acc[dx][0] * SCALE; v0.x = fmaxf(t, t * SLOPE);
    t = acc[dx][1] * SCALE; v0.y = fmaxf(t, t * SLOPE);
    t = acc[dx][2] * SCALE; v0.z = fmaxf(t, t * SLOPE);
    t = acc[dx][3] * SCALE; v0.w = fmaxf(t, t * SLOPE);
    t = acc[dx][4] * SCALE; v1.x = fmaxf(t, t * SLOPE);
    t = acc[dx][5] * SCALE; v1.y = fmaxf(t, t * SLOPE);
    t = acc[dx][6] * SCALE; v1.z = fmaxf(t, t * SLOPE);
    t = acc[dx][7] * SCALE; v1.w = fmaxf(t, t * SLOPE);
    float* po = out + obase + dx * HW;
    *reinterpret_cast<float4*>(po)     = v0;
    *reinterpret_cast<float4*>(po + 4) = v1;
  }
}

extern "C" void kernel_launch(void* const* d_in, const int* in_sizes, int n_in,
                              void* d_out, int out_size, void* d_ws, size_t ws_size,
                              hipStream_t stream) {
  const float* x1 = (const float*)d_in[0];
  const float* x2 = (const float*)d_in[1];
  float* out = (float*)d_out;
  dim3 grid(Ww / TW, Hh / TH, Bb);   // 4 x 16 x 8 = 512 blocks, 576 thr (9 waves)
  corr81_kernel<<<grid, NTHREADS, 0, stream>>>(x1, x2, out);
}

// Round 2
// 418.496 us; speedup vs baseline: 1.2923x; 1.2923x over previous
//
#include <hip/hip_runtime.h>

// FlowNet correlation, max_disp=4 -> 81 displacement channels, mean over C, LeakyReLU(0.1).
// B=8 C=128 H=128 W=256 fp32 NCHW.
//
// Block = 576 threads = 9 waves; wave wv handles displacement row dy=wv.
// Lane owns 8 consecutive pixels of an 8x64 spatial tile -> acc[9 dx][8 px] in regs.
// x2 halo tile (16 x 72, stride 76) staged in double-buffered LDS, 4 channels/chunk.
// x1 read direct from global (coalesced, 9x wave reuse via L1) with reg ping-pong.
//
// R2 fix: __launch_bounds__(576,1). R1's (576,4) clamped VGPRs to 64 -> the 72-reg
// accumulator spilled to scratch (WRITE_SIZE 180MB vs 85MB ideal, dur 355us).
// A 9-wave block packs 3 waves on one SIMD -> up to ~170 VGPRs available; live set
// ~120 fits spill-free. Occupancy 9 waves/CU is enough: each LDS read batch is
// covered by ~144 cyc of FMA from sibling waves.

constexpr int MAXD = 4;
constexpr int ND   = 9;            // displacements per axis
constexpr int NDISP = 81;
constexpr int Bb = 8, Cc = 128, Hh = 128, Ww = 256;
constexpr int TH = 8, TW = 64, NPIX = 8;
constexpr int CK = 4;              // channels per staged chunk
constexpr int NCHUNK = Cc / CK;    // 32
constexpr int XROWS = TH + 2 * MAXD;   // 16
constexpr int XSTR  = 76;              // padded row stride (72 used)
constexpr int CH_TILE = XROWS * XSTR;  // 1216 floats / channel
constexpr int BUFF = CK * CH_TILE;     // 4864 floats / buffer
constexpr int NTHREADS = ND * 64;      // 576
constexpr int HW = Hh * Ww;            // 32768
constexpr float SCALE = 1.0f / 128.0f;
constexpr float SLOPE = 0.1f;

__global__ __launch_bounds__(NTHREADS, 1)
void corr81_kernel(const float* __restrict__ x1, const float* __restrict__ x2,
                   float* __restrict__ out) {
  const int tid = threadIdx.x;
  const int wv  = tid >> 6;          // dy = wv, 0..8
  const int l   = tid & 63;
  const int r   = l >> 3;            // pixel row in tile, 0..7
  const int cb  = (l & 7) << 3;      // pixel col base, 0..56

  const int w0 = blockIdx.x * TW;
  const int h0 = blockIdx.y * TH;
  const int b  = blockIdx.z;

  __shared__ float x2s[2 * BUFF];    // 38912 B

  // --- staging coords: 576 threads x one float2 = 16 rows x 72 cols per channel
  const int srow = tid / 36;                 // 0..15
  const int scol = (tid - srow * 36) * 2;    // 0..70, even
  const int gh2  = h0 - MAXD + srow;
  const int gw2  = w0 - MAXD + scol;
  const bool sok = (gh2 >= 0) && (gh2 < Hh) && (gw2 >= 0) && (gw2 < Ww);
  const int x2base = b * (Cc * HW) + gh2 * Ww + gw2;   // valid only when sok
  const int sldso  = srow * XSTR + scol;

  // --- compute-side addresses
  const int x1base = (b * Cc * Hh + h0 + r) * Ww + w0 + cb;
  const int ldro   = (r + wv) * XSTR + cb;   // LDS row (r+dy), col cb (reads cb..cb+15)

  float acc[ND][NPIX];
#pragma unroll
  for (int dx = 0; dx < ND; ++dx)
#pragma unroll
    for (int i = 0; i < NPIX; ++i) acc[dx][i] = 0.0f;

  float a[2][NPIX];  // x1 ping-pong: channel parity ch&1

  auto loadx1 = [&](int ch, float* dst) {
    const float* p = x1 + x1base + ch * HW;
    float4 t0 = *reinterpret_cast<const float4*>(p);
    float4 t1 = *reinterpret_cast<const float4*>(p + 4);
    dst[0] = t0.x; dst[1] = t0.y; dst[2] = t0.z; dst[3] = t0.w;
    dst[4] = t1.x; dst[5] = t1.y; dst[6] = t1.z; dst[7] = t1.w;
  };

  // --- prologue: stage chunk 0, load x1 channel 0
#pragma unroll
  for (int c = 0; c < CK; ++c) {
    float2 v = make_float2(0.0f, 0.0f);
    if (sok) v = *reinterpret_cast<const float2*>(x2 + x2base + c * HW);
    *reinterpret_cast<float2*>(&x2s[c * CH_TILE + sldso]) = v;
  }
  loadx1(0, a[0]);
  __syncthreads();

  for (int k = 0; k < NCHUNK; ++k) {
    const int kn = k + 1;
    float2 sreg[CK];
    if (kn < NCHUNK) {  // issue next chunk's global loads early
#pragma unroll
      for (int c = 0; c < CK; ++c) {
        float2 v = make_float2(0.0f, 0.0f);
        if (sok) v = *reinterpret_cast<const float2*>(x2 + x2base + (kn * CK + c) * HW);
        sreg[c] = v;
      }
    }
    const float* lb = &x2s[(k & 1) * BUFF + ldro];
#pragma unroll
    for (int c = 0; c < CK; ++c) {
      const int ch = k * CK + c;
      int chn = ch + 1; if (chn >= Cc) chn = Cc - 1;   // clamped tail prefetch
      loadx1(chn, a[(c + 1) & 1]);

      const float* lp = lb + c * CH_TILE;
      float4 q0 = *reinterpret_cast<const float4*>(lp);
      float4 q1 = *reinterpret_cast<const float4*>(lp + 4);
      float4 q2 = *reinterpret_cast<const float4*>(lp + 8);
      float4 q3 = *reinterpret_cast<const float4*>(lp + 12);
      float xr[16] = {q0.x, q0.y, q0.z, q0.w, q1.x, q1.y, q1.z, q1.w,
                      q2.x, q2.y, q2.z, q2.w, q3.x, q3.y, q3.z, q3.w};
      const float* av = a[c & 1];
#pragma unroll
      for (int dx = 0; dx < ND; ++dx)
#pragma unroll
        for (int i = 0; i < NPIX; ++i)
          acc[dx][i] = fmaf(av[i], xr[i + dx], acc[dx][i]);
    }
    if (kn < NCHUNK) {  // commit next chunk into the other buffer
#pragma unroll
      for (int c = 0; c < CK; ++c)
        *reinterpret_cast<float2*>(&x2s[(kn & 1) * BUFF + c * CH_TILE + sldso]) = sreg[c];
    }
    __syncthreads();
  }

  // --- epilogue: mean + LeakyReLU + coalesced float4 stores
  const int obase = (b * NDISP + wv * ND) * HW + (h0 + r) * Ww + w0 + cb;
#pragma unroll
  for (int dx = 0; dx < ND; ++dx) {
    float4 v0, v1;
    float t;
    t = acc[dx][0] * SCALE; v0.x = fmaxf(t, t * SLOPE);
    t = acc[dx][1] * SCALE; v0.y = fmaxf(t, t * SLOPE);
    t = acc[dx][2] * SCALE; v0.z = fmaxf(t, t * SLOPE);
    t = acc[dx][3] * SCALE; v0.w = fmaxf(t, t * SLOPE);
    t = acc[dx][4] * SCALE; v1.x = fmaxf(t, t * SLOPE);
    t = acc[dx][5] * SCALE; v1.y = fmaxf(t, t * SLOPE);
    t = acc[dx][6] * SCALE; v1.z = fmaxf(t, t * SLOPE);
    t = acc[dx][7] * SCALE; v1.w = fmaxf(t, t * SLOPE);
    float* po = out + obase + dx * HW;
    *reinterpret_cast<float4*>(po)     = v0;
    *reinterpret_cast<float4*>(po + 4) = v1;
  }
}

extern "C" void kernel_launch(void* const* d_in, const int* in_sizes, int n_in,
                              void* d_out, int out_size, void* d_ws, size_t ws_size,
                              hipStream_t stream) {
  const float* x1 = (const float*)d_in[0];
  const float* x2 = (const float*)d_in[1];
  float* out = (float*)d_out;
  dim3 grid(Ww / TW, Hh / TH, Bb);   // 4 x 16 x 8 = 512 blocks, 576 thr (9 waves)
  corr81_kernel<<<grid, NTHREADS, 0, stream>>>(x1, x2, out);
}